// Round 16
// baseline (437.564 us; speedup 1.0000x reference)
//
#include <hip/hip_runtime.h>
#include <hip/hip_bf16.h>
#include <stdint.h>

#define M_DIM 16384   // B*T = 4*4096
#define K_DIM 2048    // H
#define N_DIM 6144    // 3H
#define NT    32      // K-tiles per output tile (K_DIM/64)
#define NTILES 6      // output tiles per persistent block (1536/256)

typedef __attribute__((ext_vector_type(8))) short bf16x8;
typedef __attribute__((ext_vector_type(8))) unsigned short u16x8;
typedef __attribute__((ext_vector_type(4))) float f32x4;

__device__ __forceinline__ unsigned short f2bf(float f) {
  unsigned int u = __float_as_uint(f);
  u += 0x7FFFu + ((u >> 16) & 1u);   // RNE
  return (unsigned short)(u >> 16);
}

__device__ __forceinline__ void load_lds16(const void* g, void* l) {
  __builtin_amdgcn_global_load_lds((const __attribute__((address_space(1))) void*)g,
                                   (__attribute__((address_space(3))) void*)l, 16, 0, 0);
}

#define FENCE asm volatile("" ::: "memory")
#define BAR   do { FENCE; __builtin_amdgcn_s_barrier(); FENCE; } while (0)

// ---------- Pass 1: fused input conversion ----------
__global__ __launch_bounds__(256) void cvt_fused(const float* __restrict__ hidden,
                                                 unsigned short* __restrict__ outh,
                                                 const float* __restrict__ w,
                                                 unsigned short* __restrict__ wt) {
  __shared__ float tile[64][69];
  const int bid = blockIdx.x;
  const int t = threadIdx.x;
  if (bid < 2048) {
    unsigned int base = bid * 256u + t;
    #pragma unroll
    for (int i = 0; i < 16; ++i) {
      unsigned int fi = i * 524288u + base;
      f32x4 v = __builtin_nontemporal_load(reinterpret_cast<const f32x4*>(hidden) + fi);
      ushort4 o;
      o.x = f2bf(v[0]); o.y = f2bf(v[1]); o.z = f2bf(v[2]); o.w = f2bf(v[3]);
      reinterpret_cast<ushort4*>(outh)[fi] = o;
    }
  } else {
    const int wb = bid - 2048;                  // 0..3071
    const int k0 = (wb / 96) * 64;
    const int n0 = (wb % 96) * 64;
    #pragma unroll
    for (int i = 0; i < 4; ++i) {
      int idx = i * 256 + t;
      int row = idx >> 4, c4 = idx & 15;
      f32x4 v = __builtin_nontemporal_load(reinterpret_cast<const f32x4*>(
          &w[(size_t)(k0 + row) * N_DIM + n0 + c4 * 4]));
      tile[row][c4 * 4 + 0] = v[0]; tile[row][c4 * 4 + 1] = v[1];
      tile[row][c4 * 4 + 2] = v[2]; tile[row][c4 * 4 + 3] = v[3];
    }
    __syncthreads();
    #pragma unroll
    for (int i = 0; i < 2; ++i) {
      int idx = i * 256 + t;
      int n = idx >> 3, k8 = idx & 7;
      u16x8 v;
      #pragma unroll
      for (int e = 0; e < 8; ++e) v[e] = f2bf(tile[k8 * 8 + e][n]);
      *reinterpret_cast<u16x8*>(&wt[(size_t)(n0 + n) * K_DIM + k0 + k8 * 8]) = v;
    }
  }
}

// ---------- Pass 2: persistent 256x256x64 2-phase bf16 MFMA GEMM ------------
// R16 = R15 + boundary store-shadow:
//   - epilogue (j+1<NTILES) pre-stages K1n.A{1,3} BEFORE the 32 stores
//     (dest buf[1].A13; its A-hi was last read at t=31.phB, barrier-ordered).
//   - t==0 (j>0) skips phA staging (already done) and waits vmcnt(38):
//     queue [K1n.BA02(6), K1n.A13(2), ST(32), K2n(6)] -> retiring to 38
//     completes K1n with ALL stores still in flight.
//   - first store-forced wait is t==1's vmcnt(6), by which stores had ~2
//     iterations (~4.3us) to drain into L2 (~1.9us needed) -> no stall.
// Staging-safety invariants identical to R15 (region staged only after the
//   barrier following its last read). Steady vmcnt(6); tail vmcnt(0).
// Bias folded into acc-init; pure f32x4 epilogue stores through L2.
// (R12 lesson: (t&1) selects + ternary sources are load-bearing — kept.)
__global__ __launch_bounds__(512, 2) void gemm_qkv_8ph(const unsigned short* __restrict__ A,
                                                       const unsigned short* __restrict__ Bt,
                                                       const float* __restrict__ bias,
                                                       float* __restrict__ out) {
  extern __shared__ __align__(16) char smem[];
  const int tid = threadIdx.x, lane = tid & 63, wid = tid >> 6;
  const int wm = wid >> 2, wn = wid & 3;        // 2 x 4 wave grid, 128x64 per wave

  const int xcd = blockIdx.x & 7;
  const int lcl = blockIdx.x >> 3;              // 0..31 within XCD

  const int srow  = tid >> 3;
  const int sslot = (tid & 7) ^ ((tid >> 3) & 7);
  const int r15 = lane & 15, q4 = lane >> 4, x7 = lane & 7;
  const int abase = (wm * 128 + r15) * 128;
  const int bbase = (wn * 64  + r15) * 128;
  const int sw0 = ((0 + q4) ^ x7) * 16;
  const int sw1 = ((4 + q4) ^ x7) * 16;

  #define STAGE_T(gsrc, ldsbase)                                              \
    { const unsigned short* _g = (gsrc); char* _l = (ldsbase);                \
      load_lds16(_g,                       _l +     wid * 1024);              \
      load_lds16(_g + (size_t)64  * K_DIM, _l + 8192  + wid * 1024);          \
      load_lds16(_g + (size_t)128 * K_DIM, _l + 16384 + wid * 1024);          \
      load_lds16(_g + (size_t)192 * K_DIM, _l + 24576 + wid * 1024); }

  #define STAGE_H2(gsrc, ldsbase, cA, cB)                                     \
    { const unsigned short* _g = (gsrc); char* _l = (ldsbase);                \
      load_lds16(_g + (size_t)((cA) * 64) * K_DIM, _l + (cA) * 8192 + wid * 1024); \
      load_lds16(_g + (size_t)((cB) * 64) * K_DIM, _l + (cB) * 8192 + wid * 1024); }

  #define TILE_MAP(jj, m0_, n0_, gA_, gB_)                                    \
    { const int bm_ = xcd * 8 + (lcl >> 2);                                   \
      const int bn_ = (jj) * 4 + (lcl & 3);                                   \
      m0_ = bm_ * 256; n0_ = bn_ * 256;                                       \
      gA_ = A  + (size_t)(m0_ + srow) * K_DIM + sslot * 8;                    \
      gB_ = Bt + (size_t)(n0_ + srow) * K_DIM + sslot * 8; }

  // ---- bias preload into LDS corner (once): 6 tiles x 256 floats ----
  if (tid < 384) {
    const int jj = tid / 64;
    const int o  = (tid & 63) * 4;
    const int bn_ = jj * 4 + (lcl & 3);
    f32x4 bv = *reinterpret_cast<const f32x4*>(&bias[bn_ * 256 + o]);
    *reinterpret_cast<f32x4*>(smem + 131072 + jj * 1024 + o * 4) = bv;
  }

  // ---- prologue: K0 full (8) + K1 partial B{0-3}+A{0,2} (6) ----
  int m0, n0, m0n, n0n;
  const unsigned short *gA, *gB, *gAn, *gBn;
  TILE_MAP(0, m0, n0, gA, gB);
  {
    char* A0 = smem;          char* B0 = smem + 32768;
    char* A1 = smem + 65536;  char* B1 = smem + 98304;
    STAGE_T(gB +  0, B0); STAGE_T(gA +  0, A0);
    STAGE_H2(gB + 64, B1, 0, 1); STAGE_H2(gB + 64, B1, 2, 3);
    STAGE_H2(gA + 64, A1, 0, 2);
    asm volatile("s_waitcnt vmcnt(6)" ::: "memory");   // K0 landed
    BAR;
  }

  for (int j = 0; j < NTILES; ++j) {
    const int jn = (j + 1 < NTILES) ? j + 1 : j;
    TILE_MAP(jn, m0n, n0n, gAn, gBn);

    // bias-as-acc-init: lane's 4 acc regs = 4 consecutive n-cols
    f32x4 bq[2][2];
    {
      const char* bl = smem + 131072 + j * 1024;
      #pragma unroll
      for (int qn = 0; qn < 2; ++qn)
        #pragma unroll
        for (int ni = 0; ni < 2; ++ni)
          bq[qn][ni] = *reinterpret_cast<const f32x4*>(
              bl + (wn * 64 + qn * 32 + ni * 16 + q4 * 4) * 4);
    }
    f32x4 acc[2][2][4][2];                             // [qm][qn][mi][ni]
    #pragma unroll
    for (int qm = 0; qm < 2; ++qm)
      #pragma unroll
      for (int qn = 0; qn < 2; ++qn)
        #pragma unroll
        for (int mi = 0; mi < 4; ++mi)
          #pragma unroll
          for (int ni = 0; ni < 2; ++ni)
            acc[qm][qn][mi][ni] = bq[qn][ni];

    bf16x8 a[4][2], b0[2][2], b1[2][2];

    for (int t = 0; t < NT; ++t) {
      char* Ab  = smem + (t & 1) * 65536;              // K(t)
      char* Bb  = Ab + 32768;
      char* Ab1 = smem + (((t + 1) & 1) * 65536);      // K(t+1) A13 dest
      const bool st1 = ((t + 1 < NT) || (j + 1 < NTILES)) && !(t == 0 && j != 0);
      const bool st2 = (t + 2 < NT) || (j + 1 < NTILES);
      const unsigned short* sA1 = (t + 1 < NT) ? gA + (size_t)(t + 1) * 64 : gAn;
      const unsigned short* sA2 = (t + 2 < NT) ? gA + (size_t)(t + 2) * 64
                                               : gAn + (size_t)(t + 2 - NT) * 64;
      const unsigned short* sB2 = (t + 2 < NT) ? gB + (size_t)(t + 2) * 64
                                               : gBn + (size_t)(t + 2 - NT) * 64;

      // ---- ph_A: read B(all)+A-lo; stage K(t+1).A{1,3}; MFMA qm=0 ----
      #pragma unroll
      for (int ni = 0; ni < 2; ++ni) {
        const char* p0 = Bb + bbase + ni * (16 * 128);
        b0[ni][0] = *(const bf16x8*)(p0 + sw0);
        b0[ni][1] = *(const bf16x8*)(p0 + sw1);
        const char* p1 = Bb + bbase + (32 + ni * 16) * 128;
        b1[ni][0] = *(const bf16x8*)(p1 + sw0);
        b1[ni][1] = *(const bf16x8*)(p1 + sw1);
      }
      #pragma unroll
      for (int mi = 0; mi < 4; ++mi) {
        const char* p = Ab + abase + mi * (16 * 128);
        a[mi][0] = *(const bf16x8*)(p + sw0);
        a[mi][1] = *(const bf16x8*)(p + sw1);
      }
      if (st1) STAGE_H2(sA1, Ab1, 1, 3);
      BAR;
      __builtin_amdgcn_s_setprio(1);
      #pragma unroll
      for (int mi = 0; mi < 4; ++mi)
        #pragma unroll
        for (int ni = 0; ni < 2; ++ni) {
          acc[0][0][mi][ni] = __builtin_amdgcn_mfma_f32_16x16x32_bf16(b0[ni][0], a[mi][0], acc[0][0][mi][ni], 0, 0, 0);
          acc[0][0][mi][ni] = __builtin_amdgcn_mfma_f32_16x16x32_bf16(b0[ni][1], a[mi][1], acc[0][0][mi][ni], 0, 0, 0);
          acc[0][1][mi][ni] = __builtin_amdgcn_mfma_f32_16x16x32_bf16(b1[ni][0], a[mi][0], acc[0][1][mi][ni], 0, 0, 0);
          acc[0][1][mi][ni] = __builtin_amdgcn_mfma_f32_16x16x32_bf16(b1[ni][1], a[mi][1], acc[0][1][mi][ni], 0, 0, 0);
        }
      __builtin_amdgcn_s_setprio(0);
      BAR;

      // ---- ph_B: read A-hi; stage K(t+2).B{0-3}+A{0,2}; MFMA qm=1 ----
      #pragma unroll
      for (int mi = 0; mi < 4; ++mi) {
        const char* p = Ab + abase + (64 + mi * 16) * 128;
        a[mi][0] = *(const bf16x8*)(p + sw0);
        a[mi][1] = *(const bf16x8*)(p + sw1);
      }
      if (st2) {
        STAGE_H2(sB2, Bb, 0, 1);
        STAGE_H2(sB2, Bb, 2, 3);
        STAGE_H2(sA2, Ab, 0, 2);
      }
      BAR;
      __builtin_amdgcn_s_setprio(1);
      #pragma unroll
      for (int mi = 0; mi < 4; ++mi)
        #pragma unroll
        for (int ni = 0; ni < 2; ++ni) {
          acc[1][0][mi][ni] = __builtin_amdgcn_mfma_f32_16x16x32_bf16(b0[ni][0], a[mi][0], acc[1][0][mi][ni], 0, 0, 0);
          acc[1][0][mi][ni] = __builtin_amdgcn_mfma_f32_16x16x32_bf16(b0[ni][1], a[mi][1], acc[1][0][mi][ni], 0, 0, 0);
          acc[1][1][mi][ni] = __builtin_amdgcn_mfma_f32_16x16x32_bf16(b1[ni][0], a[mi][0], acc[1][1][mi][ni], 0, 0, 0);
          acc[1][1][mi][ni] = __builtin_amdgcn_mfma_f32_16x16x32_bf16(b1[ni][1], a[mi][1], acc[1][1][mi][ni], 0, 0, 0);
        }
      __builtin_amdgcn_s_setprio(0);
      // waits: t==0 (j>0): queue [K1n.BA02(6), K1n.A13(2), ST(32), K2n(6)]
      //   -> vmcnt(38) completes K1n, stores stay in flight.
      //   steady: vmcnt(6) (K(t+1) complete). tail: vmcnt(0).
      if (!st2)              { asm volatile("s_waitcnt vmcnt(0)"  ::: "memory"); }
      else if (t == 0 && j)  { asm volatile("s_waitcnt vmcnt(38)" ::: "memory"); }
      else                   { asm volatile("s_waitcnt vmcnt(6)"  ::: "memory"); }
      BAR;
    }

    // ---- epilogue: pre-stage next tile's K1n.A{1,3}, then 32 f32x4 stores --
    if (j + 1 < NTILES) STAGE_H2(gAn + 64, smem + 65536, 1, 3);
    #pragma unroll
    for (int qm = 0; qm < 2; ++qm)
      #pragma unroll
      for (int mi = 0; mi < 4; ++mi) {
        const int m = m0 + wm * 128 + qm * 64 + mi * 16 + r15;
        const int bb_ = m >> 12, tt = m & 4095;
        float* orow = out + (size_t)bb_ * 8388608 + (size_t)tt * 128;
        #pragma unroll
        for (int qn = 0; qn < 2; ++qn)
          #pragma unroll
          for (int ni = 0; ni < 2; ++ni) {
            const int col = n0 + wn * 64 + qn * 32 + ni * 16 + q4 * 4;
            const int which = col >> 11, head = (col & 2047) >> 7, hd = col & 127;
            *reinterpret_cast<f32x4*>(orow + (size_t)which * 33554432 +
                                      (size_t)head * 524288 + hd) = acc[qm][qn][mi][ni];
          }
      }

    m0 = m0n; n0 = n0n; gA = gAn; gB = gBn;   // advance to next tile
  }
  #undef STAGE_T
  #undef STAGE_H2
  #undef TILE_MAP
}

// ---------- Fallback: naive fp32 ----------
__global__ __launch_bounds__(256) void naive_qkv(const float* __restrict__ h,
                                                 const float* __restrict__ w,
                                                 const float* __restrict__ bias,
                                                 float* __restrict__ out) {
  const int m = blockIdx.x;
  const int n = blockIdx.y * 256 + threadIdx.x;
  const float* hr = h + (size_t)m * K_DIM;
  float acc = bias[n];
  for (int k = 0; k < K_DIM; ++k) acc = fmaf(hr[k], w[(size_t)k * N_DIM + n], acc);
  const int which = n >> 11, head = (n & 2047) >> 7, hd = n & 127;
  const int bb = m >> 12, tt = m & 4095;
  out[(size_t)which * 33554432 + (size_t)bb * 8388608 + (size_t)head * 524288 +
      (size_t)tt * 128 + hd] = acc;
}

extern "C" void kernel_launch(void* const* d_in, const int* in_sizes, int n_in,
                              void* d_out, int out_size, void* d_ws, size_t ws_size,
                              hipStream_t stream) {
  const float* hidden = (const float*)d_in[0];
  const float* w_qkv  = (const float*)d_in[1];
  const float* b_qkv  = (const float*)d_in[2];
  float* out = (float*)d_out;

  const size_t needA = (size_t)M_DIM * K_DIM * 2;
  const size_t needB = (size_t)N_DIM * K_DIM * 2;
  if (ws_size >= needA + needB) {
    unsigned short* Abf = (unsigned short*)d_ws;
    unsigned short* Wt  = (unsigned short*)((char*)d_ws + needA);
    (void)hipFuncSetAttribute((const void*)gemm_qkv_8ph,
                              hipFuncAttributeMaxDynamicSharedMemorySize, 137216);
    cvt_fused<<<5120, 256, 0, stream>>>(hidden, Abf, w_qkv, Wt);
    gemm_qkv_8ph<<<256, 512, 137216, stream>>>(Abf, Wt, b_qkv, out);
  } else {
    naive_qkv<<<dim3(16384, 24), 256, 0, stream>>>(hidden, w_qkv, b_qkv, out);
  }
}

// Round 17
// 436.058 us; speedup vs baseline: 1.0035x; 1.0035x over previous
//
#include <hip/hip_runtime.h>
#include <hip/hip_bf16.h>
#include <stdint.h>

#define M_DIM 16384   // B*T = 4*4096
#define K_DIM 2048    // H
#define N_DIM 6144    // 3H
#define NT    32      // K-tiles per output tile (K_DIM/64)
#define NTILES 6      // output tiles per persistent block (1536/256)

typedef __attribute__((ext_vector_type(8))) short bf16x8;
typedef __attribute__((ext_vector_type(8))) unsigned short u16x8;
typedef __attribute__((ext_vector_type(4))) float f32x4;

__device__ __forceinline__ unsigned short f2bf(float f) {
  unsigned int u = __float_as_uint(f);
  u += 0x7FFFu + ((u >> 16) & 1u);   // RNE
  return (unsigned short)(u >> 16);
}

__device__ __forceinline__ void load_lds16(const void* g, void* l) {
  __builtin_amdgcn_global_load_lds((const __attribute__((address_space(1))) void*)g,
                                   (__attribute__((address_space(3))) void*)l, 16, 0, 0);
}

#define FENCE asm volatile("" ::: "memory")
#define BAR   do { FENCE; __builtin_amdgcn_s_barrier(); FENCE; } while (0)

// ---------- Pass 1: fused input conversion ----------
__global__ __launch_bounds__(256) void cvt_fused(const float* __restrict__ hidden,
                                                 unsigned short* __restrict__ outh,
                                                 const float* __restrict__ w,
                                                 unsigned short* __restrict__ wt) {
  __shared__ float tile[64][69];
  const int bid = blockIdx.x;
  const int t = threadIdx.x;
  if (bid < 2048) {
    unsigned int base = bid * 256u + t;
    #pragma unroll
    for (int i = 0; i < 16; ++i) {
      unsigned int fi = i * 524288u + base;
      f32x4 v = __builtin_nontemporal_load(reinterpret_cast<const f32x4*>(hidden) + fi);
      ushort4 o;
      o.x = f2bf(v[0]); o.y = f2bf(v[1]); o.z = f2bf(v[2]); o.w = f2bf(v[3]);
      reinterpret_cast<ushort4*>(outh)[fi] = o;
    }
  } else {
    const int wb = bid - 2048;                  // 0..3071
    const int k0 = (wb / 96) * 64;
    const int n0 = (wb % 96) * 64;
    #pragma unroll
    for (int i = 0; i < 4; ++i) {
      int idx = i * 256 + t;
      int row = idx >> 4, c4 = idx & 15;
      f32x4 v = __builtin_nontemporal_load(reinterpret_cast<const f32x4*>(
          &w[(size_t)(k0 + row) * N_DIM + n0 + c4 * 4]));
      tile[row][c4 * 4 + 0] = v[0]; tile[row][c4 * 4 + 1] = v[1];
      tile[row][c4 * 4 + 2] = v[2]; tile[row][c4 * 4 + 3] = v[3];
    }
    __syncthreads();
    #pragma unroll
    for (int i = 0; i < 2; ++i) {
      int idx = i * 256 + t;
      int n = idx >> 3, k8 = idx & 7;
      u16x8 v;
      #pragma unroll
      for (int e = 0; e < 8; ++e) v[e] = f2bf(tile[k8 * 8 + e][n]);
      *reinterpret_cast<u16x8*>(&wt[(size_t)(n0 + n) * K_DIM + k0 + k8 * 8]) = v;
    }
  }
}

// ---------- Pass 2: persistent 256x256x64 2-phase bf16 MFMA GEMM ------------
// R17 = R15 VERBATIM (best passing config: 433.7us total, GEMM 415.5us).
//   R16's boundary store-shadow (epilogue pre-stage + conditional phA skip)
//   regressed: SGPR 64->80 + non-uniform hot-loop branch cost more than the
//   ~1us/boundary saved. Reverted.
// Structure: 2 phases/K-iter (4 barriers), read||stage||MFMA interleave:
//   ph_A: read B(all 8)+A-lo(8); stage K(t+1).A{1,3} -> buf[(t+1)&1];
//         BAR; 32 MFMA (qm=0); BAR.
//   ph_B: read A-hi(8); stage K(t+2).B{0-3}+A{0,2} -> buf[t&1];
//         BAR; 32 MFMA (qm=1); vmcnt(6); BAR.
// Staging safety: region staged only in a phase AFTER the barrier following
//   its last read. vmcnt(6) = exact "K(t+1) complete" FIFO invariant
//   (queue [t.phA(2)=K(t+1).A13, t.phB(6)=K(t+2)]). Tail: vmcnt(0).
// Bias folded into acc-init (lane's 4 acc regs = 4 consecutive n-cols under
//   swapped-operand mfma(b,a)); epilogue = 32 pure f32x4 stores through L2.
// (R12 lesson: (t&1) selects + ternary sources are load-bearing — kept.)
__global__ __launch_bounds__(512, 2) void gemm_qkv_8ph(const unsigned short* __restrict__ A,
                                                       const unsigned short* __restrict__ Bt,
                                                       const float* __restrict__ bias,
                                                       float* __restrict__ out) {
  extern __shared__ __align__(16) char smem[];
  const int tid = threadIdx.x, lane = tid & 63, wid = tid >> 6;
  const int wm = wid >> 2, wn = wid & 3;        // 2 x 4 wave grid, 128x64 per wave

  const int xcd = blockIdx.x & 7;
  const int lcl = blockIdx.x >> 3;              // 0..31 within XCD

  const int srow  = tid >> 3;
  const int sslot = (tid & 7) ^ ((tid >> 3) & 7);
  const int r15 = lane & 15, q4 = lane >> 4, x7 = lane & 7;
  const int abase = (wm * 128 + r15) * 128;
  const int bbase = (wn * 64  + r15) * 128;
  const int sw0 = ((0 + q4) ^ x7) * 16;
  const int sw1 = ((4 + q4) ^ x7) * 16;

  #define STAGE_T(gsrc, ldsbase)                                              \
    { const unsigned short* _g = (gsrc); char* _l = (ldsbase);                \
      load_lds16(_g,                       _l +     wid * 1024);              \
      load_lds16(_g + (size_t)64  * K_DIM, _l + 8192  + wid * 1024);          \
      load_lds16(_g + (size_t)128 * K_DIM, _l + 16384 + wid * 1024);          \
      load_lds16(_g + (size_t)192 * K_DIM, _l + 24576 + wid * 1024); }

  #define STAGE_H2(gsrc, ldsbase, cA, cB)                                     \
    { const unsigned short* _g = (gsrc); char* _l = (ldsbase);                \
      load_lds16(_g + (size_t)((cA) * 64) * K_DIM, _l + (cA) * 8192 + wid * 1024); \
      load_lds16(_g + (size_t)((cB) * 64) * K_DIM, _l + (cB) * 8192 + wid * 1024); }

  #define TILE_MAP(jj, m0_, n0_, gA_, gB_)                                    \
    { const int bm_ = xcd * 8 + (lcl >> 2);                                   \
      const int bn_ = (jj) * 4 + (lcl & 3);                                   \
      m0_ = bm_ * 256; n0_ = bn_ * 256;                                       \
      gA_ = A  + (size_t)(m0_ + srow) * K_DIM + sslot * 8;                    \
      gB_ = Bt + (size_t)(n0_ + srow) * K_DIM + sslot * 8; }

  // ---- bias preload into LDS corner (once): 6 tiles x 256 floats ----
  if (tid < 384) {
    const int jj = tid / 64;
    const int o  = (tid & 63) * 4;
    const int bn_ = jj * 4 + (lcl & 3);
    f32x4 bv = *reinterpret_cast<const f32x4*>(&bias[bn_ * 256 + o]);
    *reinterpret_cast<f32x4*>(smem + 131072 + jj * 1024 + o * 4) = bv;
  }

  // ---- prologue: K0 full (8) + K1 partial B{0-3}+A{0,2} (6) ----
  int m0, n0, m0n, n0n;
  const unsigned short *gA, *gB, *gAn, *gBn;
  TILE_MAP(0, m0, n0, gA, gB);
  {
    char* A0 = smem;          char* B0 = smem + 32768;
    char* A1 = smem + 65536;  char* B1 = smem + 98304;
    STAGE_T(gB +  0, B0); STAGE_T(gA +  0, A0);
    STAGE_H2(gB + 64, B1, 0, 1); STAGE_H2(gB + 64, B1, 2, 3);
    STAGE_H2(gA + 64, A1, 0, 2);
    asm volatile("s_waitcnt vmcnt(6)" ::: "memory");   // K0 landed
    BAR;
  }

  for (int j = 0; j < NTILES; ++j) {
    const int jn = (j + 1 < NTILES) ? j + 1 : j;
    TILE_MAP(jn, m0n, n0n, gAn, gBn);

    // bias-as-acc-init: lane's 4 acc regs = 4 consecutive n-cols
    f32x4 bq[2][2];
    {
      const char* bl = smem + 131072 + j * 1024;
      #pragma unroll
      for (int qn = 0; qn < 2; ++qn)
        #pragma unroll
        for (int ni = 0; ni < 2; ++ni)
          bq[qn][ni] = *reinterpret_cast<const f32x4*>(
              bl + (wn * 64 + qn * 32 + ni * 16 + q4 * 4) * 4);
    }
    f32x4 acc[2][2][4][2];                             // [qm][qn][mi][ni]
    #pragma unroll
    for (int qm = 0; qm < 2; ++qm)
      #pragma unroll
      for (int qn = 0; qn < 2; ++qn)
        #pragma unroll
        for (int mi = 0; mi < 4; ++mi)
          #pragma unroll
          for (int ni = 0; ni < 2; ++ni)
            acc[qm][qn][mi][ni] = bq[qn][ni];

    bf16x8 a[4][2], b0[2][2], b1[2][2];

    for (int t = 0; t < NT; ++t) {
      char* Ab  = smem + (t & 1) * 65536;              // K(t)
      char* Bb  = Ab + 32768;
      char* Ab1 = smem + (((t + 1) & 1) * 65536);      // K(t+1) A13 dest
      const bool st1 = (t + 1 < NT) || (j + 1 < NTILES);
      const bool st2 = (t + 2 < NT) || (j + 1 < NTILES);
      const unsigned short* sA1 = (t + 1 < NT) ? gA + (size_t)(t + 1) * 64 : gAn;
      const unsigned short* sA2 = (t + 2 < NT) ? gA + (size_t)(t + 2) * 64
                                               : gAn + (size_t)(t + 2 - NT) * 64;
      const unsigned short* sB2 = (t + 2 < NT) ? gB + (size_t)(t + 2) * 64
                                               : gBn + (size_t)(t + 2 - NT) * 64;

      // ---- ph_A: read B(all)+A-lo; stage K(t+1).A{1,3}; MFMA qm=0 ----
      #pragma unroll
      for (int ni = 0; ni < 2; ++ni) {
        const char* p0 = Bb + bbase + ni * (16 * 128);
        b0[ni][0] = *(const bf16x8*)(p0 + sw0);
        b0[ni][1] = *(const bf16x8*)(p0 + sw1);
        const char* p1 = Bb + bbase + (32 + ni * 16) * 128;
        b1[ni][0] = *(const bf16x8*)(p1 + sw0);
        b1[ni][1] = *(const bf16x8*)(p1 + sw1);
      }
      #pragma unroll
      for (int mi = 0; mi < 4; ++mi) {
        const char* p = Ab + abase + mi * (16 * 128);
        a[mi][0] = *(const bf16x8*)(p + sw0);
        a[mi][1] = *(const bf16x8*)(p + sw1);
      }
      if (st1) STAGE_H2(sA1, Ab1, 1, 3);
      BAR;
      __builtin_amdgcn_s_setprio(1);
      #pragma unroll
      for (int mi = 0; mi < 4; ++mi)
        #pragma unroll
        for (int ni = 0; ni < 2; ++ni) {
          acc[0][0][mi][ni] = __builtin_amdgcn_mfma_f32_16x16x32_bf16(b0[ni][0], a[mi][0], acc[0][0][mi][ni], 0, 0, 0);
          acc[0][0][mi][ni] = __builtin_amdgcn_mfma_f32_16x16x32_bf16(b0[ni][1], a[mi][1], acc[0][0][mi][ni], 0, 0, 0);
          acc[0][1][mi][ni] = __builtin_amdgcn_mfma_f32_16x16x32_bf16(b1[ni][0], a[mi][0], acc[0][1][mi][ni], 0, 0, 0);
          acc[0][1][mi][ni] = __builtin_amdgcn_mfma_f32_16x16x32_bf16(b1[ni][1], a[mi][1], acc[0][1][mi][ni], 0, 0, 0);
        }
      __builtin_amdgcn_s_setprio(0);
      BAR;

      // ---- ph_B: read A-hi; stage K(t+2).B{0-3}+A{0,2}; MFMA qm=1 ----
      #pragma unroll
      for (int mi = 0; mi < 4; ++mi) {
        const char* p = Ab + abase + (64 + mi * 16) * 128;
        a[mi][0] = *(const bf16x8*)(p + sw0);
        a[mi][1] = *(const bf16x8*)(p + sw1);
      }
      if (st2) {
        STAGE_H2(sB2, Bb, 0, 1);
        STAGE_H2(sB2, Bb, 2, 3);
        STAGE_H2(sA2, Ab, 0, 2);
      }
      BAR;
      __builtin_amdgcn_s_setprio(1);
      #pragma unroll
      for (int mi = 0; mi < 4; ++mi)
        #pragma unroll
        for (int ni = 0; ni < 2; ++ni) {
          acc[1][0][mi][ni] = __builtin_amdgcn_mfma_f32_16x16x32_bf16(b0[ni][0], a[mi][0], acc[1][0][mi][ni], 0, 0, 0);
          acc[1][0][mi][ni] = __builtin_amdgcn_mfma_f32_16x16x32_bf16(b0[ni][1], a[mi][1], acc[1][0][mi][ni], 0, 0, 0);
          acc[1][1][mi][ni] = __builtin_amdgcn_mfma_f32_16x16x32_bf16(b1[ni][0], a[mi][0], acc[1][1][mi][ni], 0, 0, 0);
          acc[1][1][mi][ni] = __builtin_amdgcn_mfma_f32_16x16x32_bf16(b1[ni][1], a[mi][1], acc[1][1][mi][ni], 0, 0, 0);
        }
      __builtin_amdgcn_s_setprio(0);
      // queue: [t.phA(2)=K(t+1).A13, t.phB(6)=K(t+2)] -> vmcnt(6) = K(t+1)
      // complete (uniform, incl. t==0 where older stores retire too).
      if (st2) { asm volatile("s_waitcnt vmcnt(6)" ::: "memory"); }
      else     { asm volatile("s_waitcnt vmcnt(0)" ::: "memory"); }
      BAR;
    }

    // ---- epilogue: 32 pure f32x4 stores (bias already in acc) ----
    #pragma unroll
    for (int qm = 0; qm < 2; ++qm)
      #pragma unroll
      for (int mi = 0; mi < 4; ++mi) {
        const int m = m0 + wm * 128 + qm * 64 + mi * 16 + r15;
        const int bb_ = m >> 12, tt = m & 4095;
        float* orow = out + (size_t)bb_ * 8388608 + (size_t)tt * 128;
        #pragma unroll
        for (int qn = 0; qn < 2; ++qn)
          #pragma unroll
          for (int ni = 0; ni < 2; ++ni) {
            const int col = n0 + wn * 64 + qn * 32 + ni * 16 + q4 * 4;
            const int which = col >> 11, head = (col & 2047) >> 7, hd = col & 127;
            *reinterpret_cast<f32x4*>(orow + (size_t)which * 33554432 +
                                      (size_t)head * 524288 + hd) = acc[qm][qn][mi][ni];
          }
      }

    m0 = m0n; n0 = n0n; gA = gAn; gB = gBn;   // advance to next tile
  }
  #undef STAGE_T
  #undef STAGE_H2
  #undef TILE_MAP
}

// ---------- Fallback: naive fp32 ----------
__global__ __launch_bounds__(256) void naive_qkv(const float* __restrict__ h,
                                                 const float* __restrict__ w,
                                                 const float* __restrict__ bias,
                                                 float* __restrict__ out) {
  const int m = blockIdx.x;
  const int n = blockIdx.y * 256 + threadIdx.x;
  const float* hr = h + (size_t)m * K_DIM;
  float acc = bias[n];
  for (int k = 0; k < K_DIM; ++k) acc = fmaf(hr[k], w[(size_t)k * N_DIM + n], acc);
  const int which = n >> 11, head = (n & 2047) >> 7, hd = n & 127;
  const int bb = m >> 12, tt = m & 4095;
  out[(size_t)which * 33554432 + (size_t)bb * 8388608 + (size_t)head * 524288 +
      (size_t)tt * 128 + hd] = acc;
}

extern "C" void kernel_launch(void* const* d_in, const int* in_sizes, int n_in,
                              void* d_out, int out_size, void* d_ws, size_t ws_size,
                              hipStream_t stream) {
  const float* hidden = (const float*)d_in[0];
  const float* w_qkv  = (const float*)d_in[1];
  const float* b_qkv  = (const float*)d_in[2];
  float* out = (float*)d_out;

  const size_t needA = (size_t)M_DIM * K_DIM * 2;
  const size_t needB = (size_t)N_DIM * K_DIM * 2;
  if (ws_size >= needA + needB) {
    unsigned short* Abf = (unsigned short*)d_ws;
    unsigned short* Wt  = (unsigned short*)((char*)d_ws + needA);
    (void)hipFuncSetAttribute((const void*)gemm_qkv_8ph,
                              hipFuncAttributeMaxDynamicSharedMemorySize, 137216);
    cvt_fused<<<5120, 256, 0, stream>>>(hidden, Abf, w_qkv, Wt);
    gemm_qkv_8ph<<<256, 512, 137216, stream>>>(Abf, Wt, b_qkv, out);
  } else {
    naive_qkv<<<dim3(16384, 24), 256, 0, stream>>>(hidden, w_qkv, b_qkv, out);
  }
}